// Round 1
// baseline (352.352 us; speedup 1.0000x reference)
//
#include <hip/hip_runtime.h>
#include <math.h>

// NoisyTopkRouter: fused dual-GEMM + softplus-noise + top2 + softmax-scatter.
// A [32768,1024] fp32, W_route/W_noise [64,1024] fp32, noise [32768,64] fp32.
// out = [32768*64 router_output floats][32768*2 indices-as-floats]

#define T_TOKENS   32768
#define D_MODEL    1024
#define NE         64      // experts
#define NCOL       128     // 2*NE fused output columns
#define M_TILE     64      // tokens per block
#define KB         16      // k-chunk
#define AS_LD      68      // padded LDS stride for A tile (16B-aligned rows)
#define WS_LD      132     // padded LDS stride for W tile
#define CS_LD      68      // padded LDS stride for noisy-logits tile [expert][token]
#define OUT_IDX_BASE ((size_t)T_TOKENS * NE)

__device__ __forceinline__ float softplus_f(float x) {
    // stable log1p(exp(x)) == max(x,0) + log1p(exp(-|x|)); matches jax.nn.softplus
    return fmaxf(x, 0.f) + log1pf(expf(-fabsf(x)));
}

__global__ __launch_bounds__(128) void router_kernel(
    const float* __restrict__ A,      // [T, D]
    const float* __restrict__ noise,  // [T, NE]
    const float* __restrict__ Wr,     // [NE, D]
    const float* __restrict__ br,     // [NE]
    const float* __restrict__ Wn,     // [NE, D]
    const float* __restrict__ bn,     // [NE]
    float* __restrict__ out)
{
    __shared__ float As[KB * AS_LD];          // A tile, k-major: As[k][m]
    __shared__ float Ws[KB * WS_LD];          // W tile, k-major: Ws[k][n], n<64 route, n>=64 noise
    __shared__ float Cs[NE * CS_LD];          // noisy logits: Cs[e][t]
    __shared__ float s_p1[M_TILE], s_p2[M_TILE];
    __shared__ int   s_e1[M_TILE], s_e2[M_TILE];

    const int tid = threadIdx.x;
    const int tx  = tid & 15;    // col group: cols tx*4..tx*4+3 and +64
    const int ty  = tid >> 4;    // 0..7 token group: tokens ty*4..+3 and +32
    const int m0  = blockIdx.x * M_TILE;

    // ---- loader lane mapping: kq = k-quad within chunk, tA = row index ----
    const int kq = tid & 3;       // 0..3 -> k offset kq*4
    const int tA = tid >> 2;      // 0..31

    const float* pA0 = A  + (size_t)(m0 + tA) * D_MODEL + kq * 4;
    const float* pA1 = pA0 + (size_t)32 * D_MODEL;
    const float* pW0 = Wr + (size_t)tA * D_MODEL + kq * 4;       // rows 0..31
    const float* pW1 = pW0 + (size_t)32 * D_MODEL;               // rows 32..63
    const float* pW2 = Wn + (size_t)tA * D_MODEL + kq * 4;       // cols 64..95
    const float* pW3 = pW2 + (size_t)32 * D_MODEL;               // cols 96..127

    float4 aR0, aR1, wR0, wR1, wR2, wR3;

#define LOAD_CHUNK(k0_) do {                         \
        aR0 = *(const float4*)(pA0 + (k0_));          \
        aR1 = *(const float4*)(pA1 + (k0_));          \
        wR0 = *(const float4*)(pW0 + (k0_));          \
        wR1 = *(const float4*)(pW1 + (k0_));          \
        wR2 = *(const float4*)(pW2 + (k0_));          \
        wR3 = *(const float4*)(pW3 + (k0_));          \
    } while (0)

    float acc[8][8];
    #pragma unroll
    for (int i = 0; i < 8; ++i)
        #pragma unroll
        for (int j = 0; j < 8; ++j) acc[i][j] = 0.f;

    LOAD_CHUNK(0);

    const int NCHUNK = D_MODEL / KB;  // 64
    for (int kc = 0; kc < NCHUNK; ++kc) {
        __syncthreads();  // previous chunk's compute done reading LDS
        // transposed store into LDS (k-major)
        {
            int sa = kq * 4 * AS_LD + tA;
            As[sa + 0 * AS_LD] = aR0.x; As[sa + 1 * AS_LD] = aR0.y;
            As[sa + 2 * AS_LD] = aR0.z; As[sa + 3 * AS_LD] = aR0.w;
            As[sa + 0 * AS_LD + 32] = aR1.x; As[sa + 1 * AS_LD + 32] = aR1.y;
            As[sa + 2 * AS_LD + 32] = aR1.z; As[sa + 3 * AS_LD + 32] = aR1.w;
            int sw = kq * 4 * WS_LD + tA;
            Ws[sw + 0 * WS_LD] = wR0.x; Ws[sw + 1 * WS_LD] = wR0.y;
            Ws[sw + 2 * WS_LD] = wR0.z; Ws[sw + 3 * WS_LD] = wR0.w;
            Ws[sw + 0 * WS_LD + 32] = wR1.x; Ws[sw + 1 * WS_LD + 32] = wR1.y;
            Ws[sw + 2 * WS_LD + 32] = wR1.z; Ws[sw + 3 * WS_LD + 32] = wR1.w;
            Ws[sw + 0 * WS_LD + 64] = wR2.x; Ws[sw + 1 * WS_LD + 64] = wR2.y;
            Ws[sw + 2 * WS_LD + 64] = wR2.z; Ws[sw + 3 * WS_LD + 64] = wR2.w;
            Ws[sw + 0 * WS_LD + 96] = wR3.x; Ws[sw + 1 * WS_LD + 96] = wR3.y;
            Ws[sw + 2 * WS_LD + 96] = wR3.z; Ws[sw + 3 * WS_LD + 96] = wR3.w;
        }
        __syncthreads();
        if (kc + 1 < NCHUNK) LOAD_CHUNK((kc + 1) * KB);  // prefetch overlaps compute

        #pragma unroll
        for (int k = 0; k < KB; ++k) {
            float4 a0 = *(const float4*)&As[k * AS_LD + ty * 4];
            float4 a1 = *(const float4*)&As[k * AS_LD + ty * 4 + 32];
            float4 w0 = *(const float4*)&Ws[k * WS_LD + tx * 4];
            float4 w1 = *(const float4*)&Ws[k * WS_LD + tx * 4 + 64];
            float am[8] = {a0.x, a0.y, a0.z, a0.w, a1.x, a1.y, a1.z, a1.w};
            float wm[8] = {w0.x, w0.y, w0.z, w0.w, w1.x, w1.y, w1.z, w1.w};
            #pragma unroll
            for (int i = 0; i < 8; ++i)
                #pragma unroll
                for (int j = 0; j < 8; ++j)
                    acc[i][j] = fmaf(am[i], wm[j], acc[i][j]);
        }
    }

    // ---- epilogue: noisy = logit + noise * softplus(noise_logit) ----
    __syncthreads();  // done with As/Ws; Cs is separate but sync before top2 reads anyway
    {
        float4 brv = *(const float4*)(br + tx * 4);
        float4 bnv = *(const float4*)(bn + tx * 4);
        float bra[4] = {brv.x, brv.y, brv.z, brv.w};
        float bna[4] = {bnv.x, bnv.y, bnv.z, bnv.w};
        #pragma unroll
        for (int i = 0; i < 8; ++i) {
            int t = ty * 4 + (i & 3) + ((i >> 2) * 32);
            float4 nz = *(const float4*)(noise + (size_t)(m0 + t) * NE + tx * 4);
            float nza[4] = {nz.x, nz.y, nz.z, nz.w};
            #pragma unroll
            for (int j = 0; j < 4; ++j) {
                float lg = acc[i][j]     + bra[j];
                float nl = acc[i][j + 4] + bna[j];
                float v  = fmaf(nza[j], softplus_f(nl), lg);
                Cs[(tx * 4 + j) * CS_LD + t] = v;
            }
        }
    }
    __syncthreads();

    // ---- top-2 + softmax: one thread per token ----
    if (tid < M_TILE) {
        const int t = tid;
        float v1 = -INFINITY, v2 = -INFINITY;
        int e1 = 0, e2 = 0;
        #pragma unroll 8
        for (int e = 0; e < NE; ++e) {
            float v = Cs[e * CS_LD + t];
            if (v > v1) { v2 = v1; e2 = e1; v1 = v; e1 = e; }
            else if (v > v2) { v2 = v; e2 = e; }
        }
        float ex = expf(v2 - v1);
        float denom = 1.f + ex;
        s_p1[t] = 1.f / denom;
        s_p2[t] = ex / denom;
        s_e1[t] = e1;
        s_e2[t] = e2;
        float2 iv = make_float2((float)e1, (float)e2);
        *(float2*)(out + OUT_IDX_BASE + (size_t)(m0 + t) * 2) = iv;
    }
    __syncthreads();

    // ---- coalesced scatter write of router_output tile [64 tokens x 64 experts] ----
    #pragma unroll
    for (int i = 0; i < 8; ++i) {
        int idx = tid + i * 128;          // 0..1023
        int t   = idx >> 4;
        int e0  = (idx & 15) * 4;
        float p1 = s_p1[t], p2 = s_p2[t];
        int   e1 = s_e1[t], e2 = s_e2[t];
        float4 v;
        v.x = (e0 + 0 == e1) ? p1 : ((e0 + 0 == e2) ? p2 : 0.f);
        v.y = (e0 + 1 == e1) ? p1 : ((e0 + 1 == e2) ? p2 : 0.f);
        v.z = (e0 + 2 == e1) ? p1 : ((e0 + 2 == e2) ? p2 : 0.f);
        v.w = (e0 + 3 == e1) ? p1 : ((e0 + 3 == e2) ? p2 : 0.f);
        *(float4*)(out + (size_t)(m0 + t) * NE + e0) = v;
    }
}

extern "C" void kernel_launch(void* const* d_in, const int* in_sizes, int n_in,
                              void* d_out, int out_size, void* d_ws, size_t ws_size,
                              hipStream_t stream) {
    const float* A     = (const float*)d_in[0];
    const float* noise = (const float*)d_in[1];
    const float* Wr    = (const float*)d_in[2];
    const float* br    = (const float*)d_in[3];
    const float* Wn    = (const float*)d_in[4];
    const float* bn    = (const float*)d_in[5];
    float* out = (float*)d_out;

    dim3 grid(T_TOKENS / M_TILE);   // 512 blocks
    dim3 block(128);
    router_kernel<<<grid, block, 0, stream>>>(A, noise, Wr, br, Wn, bn, out);
}

// Round 2
// 235.553 us; speedup vs baseline: 1.4959x; 1.4959x over previous
//
#include <hip/hip_runtime.h>
#include <math.h>

// NoisyTopkRouter via bf16x2-split MFMA:
//   C = A*W^T computed as Ah*Wh + Ah*Wl + Al*Wh  (fp32 acc, 16x16x32 bf16 MFMA)
// Kernel 1 (prepack): W_route/W_noise fp32 -> Bh/Bl bf16 in d_ws, MFMA B-frag order.
// Kernel 2 (router): A staged fp32->hi/lo bf16 in LDS (double-buffered), B frags
//   read straight from L2-resident d_ws; fused softplus-noise + top2 + scatter.

#define T_TOKENS 32768
#define D_MODEL  1024
#define NE       64
#define NCOL     128
#define M_TILE   64
#define KB       32
#define NCHUNK   (D_MODEL / KB)        // 32
#define CS_LD    65
#define OUT_IDX_BASE ((size_t)T_TOKENS * NE)
#define W_ELEMS  (NCOL * D_MODEL)      // 131072 per (hi|lo) plane

typedef short  bf16x8  __attribute__((ext_vector_type(8)));   // 8 bf16 = 4 VGPRs
typedef float  floatx4 __attribute__((ext_vector_type(4)));

__device__ __forceinline__ unsigned short f32_to_bf16_rne(float x) {
    unsigned u = __float_as_uint(x);
    unsigned r = u + 0x7fffu + ((u >> 16) & 1u);
    return (unsigned short)(r >> 16);
}
__device__ __forceinline__ float bf16_bits_to_f32(unsigned short h) {
    return __uint_as_float(((unsigned)h) << 16);
}
__device__ __forceinline__ int4 pack8(const unsigned short* h) {
    int4 r;
    r.x = (int)((unsigned)h[0] | ((unsigned)h[1] << 16));
    r.y = (int)((unsigned)h[2] | ((unsigned)h[3] << 16));
    r.z = (int)((unsigned)h[4] | ((unsigned)h[5] << 16));
    r.w = (int)((unsigned)h[6] | ((unsigned)h[7] << 16));
    return r;
}
__device__ __forceinline__ float softplus_f(float x) {
    return fmaxf(x, 0.f) + log1pf(expf(-fabsf(x)));
}

// ---------------- prepack: W -> hi/lo bf16 in B-frag order ----------------
// B-frag addressing (GEMM side): frag for (ntile, kgrp) read by lane(n16,quad):
//   elem index = ((ntile*128 + kgrp)*16 + n16)*8 + j,  value = W[ntile*16+n16][kgrp*8+j]
__global__ __launch_bounds__(256) void prepack_w(
    const float* __restrict__ Wr, const float* __restrict__ Wn,
    short* __restrict__ Bh, short* __restrict__ Bl)
{
    int g   = blockIdx.x * 256 + threadIdx.x;   // 16384 groups of 8 k
    int n   = g & 15;
    int kg  = (g >> 4) & 127;
    int t2  = g >> 11;
    int col = t2 * 16 + n;
    const float* src = (col < NE ? Wr + (size_t)col * D_MODEL
                                 : Wn + (size_t)(col - NE) * D_MODEL) + kg * 8;
    float4 a = *(const float4*)src;
    float4 b = *(const float4*)(src + 4);
    float v[8] = {a.x, a.y, a.z, a.w, b.x, b.y, b.z, b.w};
    unsigned short h[8], l[8];
    #pragma unroll
    for (int j = 0; j < 8; ++j) {
        h[j] = f32_to_bf16_rne(v[j]);
        l[j] = f32_to_bf16_rne(v[j] - bf16_bits_to_f32(h[j]));
    }
    *(int4*)(Bh + (size_t)g * 8) = pack8(h);
    *(int4*)(Bl + (size_t)g * 8) = pack8(l);
}

// ---------------- main fused kernel ----------------
__global__ __launch_bounds__(256) void router_mfma(
    const float* __restrict__ A,      // [T, D]
    const float* __restrict__ noise,  // [T, NE]
    const float* __restrict__ br,     // [NE]
    const float* __restrict__ bn,     // [NE]
    const short* __restrict__ Bh,     // packed W hi
    const short* __restrict__ Bl,     // packed W lo
    float* __restrict__ out)
{
    // A chunk, hi/lo, double buffered: elem index (kgrp*64 + m)*8 + j
    __shared__ __align__(16) short Ah[2][M_TILE * KB];
    __shared__ __align__(16) short Al[2][M_TILE * KB];
    __shared__ float Cs[NCOL * CS_LD];
    __shared__ float s_p1[M_TILE], s_p2[M_TILE];
    __shared__ int   s_e1[M_TILE], s_e2[M_TILE];

    const int tid  = threadIdx.x;
    const int lane = tid & 63;
    const int wid  = tid >> 6;
    const int wm   = wid & 1;    // wave m-group: rows wm*32..+31
    const int wn   = wid >> 1;   // wave n-group: cols wn*64..+63
    const int n16  = lane & 15;
    const int quad = lane >> 4;
    const int m0   = blockIdx.x * M_TILE;

    // staging mapping: thread -> (kgrp ks, row ms) of the chunk
    const int ms = tid & 63;
    const int ks = tid >> 6;
    const float* pA = A + (size_t)(m0 + ms) * D_MODEL + ks * 8;
    const int sgbase = (ks * 64 + ms) * 8;   // LDS elem base (16B-aligned)

    // B frag per-lane offset
    const int bLaneOff = (quad * 16 + n16) * 8;
    const size_t bWaveBase = (size_t)(wn * 4) * 16384 + bLaneOff;  // + nf*16384 + kc*512

    floatx4 acc[2][4];
    #pragma unroll
    for (int i = 0; i < 2; ++i)
        #pragma unroll
        for (int j = 0; j < 4; ++j) acc[i][j] = (floatx4)0.f;

    // ---- preload chunk 0 ----
    float4 g0 = *(const float4*)pA;
    float4 g1 = *(const float4*)(pA + 4);
    {
        float v[8] = {g0.x, g0.y, g0.z, g0.w, g1.x, g1.y, g1.z, g1.w};
        unsigned short h[8], l[8];
        #pragma unroll
        for (int j = 0; j < 8; ++j) {
            h[j] = f32_to_bf16_rne(v[j]);
            l[j] = f32_to_bf16_rne(v[j] - bf16_bits_to_f32(h[j]));
        }
        *(int4*)&Ah[0][sgbase] = pack8(h);
        *(int4*)&Al[0][sgbase] = pack8(l);
    }
    bf16x8 bhc[4], blc[4];
    #pragma unroll
    for (int nf = 0; nf < 4; ++nf) {
        size_t o = bWaveBase + (size_t)nf * 16384;
        bhc[nf] = *(const bf16x8*)(Bh + o);
        blc[nf] = *(const bf16x8*)(Bl + o);
    }

    for (int kc = 0; kc < NCHUNK; ++kc) {
        const int cur = kc & 1, nxt = cur ^ 1;
        __syncthreads();   // chunk kc staged; prior reads of buf nxt done

        // prefetch A global for chunk kc+1 (doesn't block MFMA)
        float4 n0, n1;
        if (kc + 1 < NCHUNK) {
            n0 = *(const float4*)(pA + (kc + 1) * KB);
            n1 = *(const float4*)(pA + (kc + 1) * KB + 4);
        }

        // A frags from LDS (conflict-free: consecutive 16B per lane)
        bf16x8 afh[2], afl[2];
        #pragma unroll
        for (int mf = 0; mf < 2; ++mf) {
            int g = (quad * 64 + wm * 32 + mf * 16 + n16) * 8;
            afh[mf] = *(const bf16x8*)&Ah[cur][g];
            afl[mf] = *(const bf16x8*)&Al[cur][g];
        }

        // prefetch B frags for kc+1 (L2-resident)
        bf16x8 bhn[4], bln[4];
        if (kc + 1 < NCHUNK) {
            #pragma unroll
            for (int nf = 0; nf < 4; ++nf) {
                size_t o = bWaveBase + (size_t)nf * 16384 + (size_t)(kc + 1) * 512;
                bhn[nf] = *(const bf16x8*)(Bh + o);
                bln[nf] = *(const bf16x8*)(Bl + o);
            }
        }

        // 24 MFMAs: Ah*Wh + Ah*Wl + Al*Wh
        #pragma unroll
        for (int mf = 0; mf < 2; ++mf)
            #pragma unroll
            for (int nf = 0; nf < 4; ++nf) {
                acc[mf][nf] = __builtin_amdgcn_mfma_f32_16x16x32_bf16(afh[mf], bhc[nf], acc[mf][nf], 0, 0, 0);
                acc[mf][nf] = __builtin_amdgcn_mfma_f32_16x16x32_bf16(afh[mf], blc[nf], acc[mf][nf], 0, 0, 0);
                acc[mf][nf] = __builtin_amdgcn_mfma_f32_16x16x32_bf16(afl[mf], bhc[nf], acc[mf][nf], 0, 0, 0);
            }

        // stage chunk kc+1 into the other buffer
        if (kc + 1 < NCHUNK) {
            float v[8] = {n0.x, n0.y, n0.z, n0.w, n1.x, n1.y, n1.z, n1.w};
            unsigned short h[8], l[8];
            #pragma unroll
            for (int j = 0; j < 8; ++j) {
                h[j] = f32_to_bf16_rne(v[j]);
                l[j] = f32_to_bf16_rne(v[j] - bf16_bits_to_f32(h[j]));
            }
            *(int4*)&Ah[nxt][sgbase] = pack8(h);
            *(int4*)&Al[nxt][sgbase] = pack8(l);
            #pragma unroll
            for (int nf = 0; nf < 4; ++nf) { bhc[nf] = bhn[nf]; blc[nf] = bln[nf]; }
        }
    }

    // ---- epilogue: accs -> Cs[col][token] (raw logits, both halves) ----
    // D layout: col = lane&15 (n within frag), row = quad*4 + r (m within frag)
    #pragma unroll
    for (int mf = 0; mf < 2; ++mf)
        #pragma unroll
        for (int nf = 0; nf < 4; ++nf) {
            int col = wn * 64 + nf * 16 + n16;
            int tb  = wm * 32 + mf * 16 + quad * 4;
            #pragma unroll
            for (int r = 0; r < 4; ++r)
                Cs[col * CS_LD + tb + r] = acc[mf][nf][r];
        }
    __syncthreads();

    // ---- fuse: noisy = route + noise * softplus(noise_logit), in place ----
    {
        const int e  = tid & 63;
        const int th = tid >> 6;   // token group *16
        float brv = br[e], bnv = bn[e];
        #pragma unroll
        for (int j = 0; j < 16; ++j) {
            int t = th * 16 + j;
            float route = Cs[e * CS_LD + t] + brv;
            float nl    = Cs[(e + NE) * CS_LD + t] + bnv;
            float nz    = noise[(size_t)(m0 + t) * NE + e];
            Cs[e * CS_LD + t] = fmaf(nz, softplus_f(nl), route);
        }
    }
    __syncthreads();

    // ---- top-2 + softmax (one thread per token) ----
    if (tid < M_TILE) {
        const int t = tid;
        float v1 = -INFINITY, v2 = -INFINITY;
        int e1 = 0, e2 = 0;
        #pragma unroll 8
        for (int e = 0; e < NE; ++e) {
            float v = Cs[e * CS_LD + t];
            if (v > v1) { v2 = v1; e2 = e1; v1 = v; e1 = e; }
            else if (v > v2) { v2 = v; e2 = e; }
        }
        float ex = expf(v2 - v1);
        float denom = 1.f + ex;
        s_p1[t] = 1.f / denom;
        s_p2[t] = ex / denom;
        s_e1[t] = e1;
        s_e2[t] = e2;
        float2 iv = make_float2((float)e1, (float)e2);
        *(float2*)(out + OUT_IDX_BASE + (size_t)(m0 + t) * 2) = iv;
    }
    __syncthreads();

    // ---- coalesced scatter of router_output [64 tokens x 64 experts] ----
    #pragma unroll
    for (int i = 0; i < 4; ++i) {
        int gi = i * 256 + tid;       // 0..1023
        int t  = gi >> 4;
        int e0 = (gi & 15) * 4;
        float p1 = s_p1[t], p2 = s_p2[t];
        int   e1 = s_e1[t], e2 = s_e2[t];
        float4 v;
        v.x = (e0 + 0 == e1) ? p1 : ((e0 + 0 == e2) ? p2 : 0.f);
        v.y = (e0 + 1 == e1) ? p1 : ((e0 + 1 == e2) ? p2 : 0.f);
        v.z = (e0 + 2 == e1) ? p1 : ((e0 + 2 == e2) ? p2 : 0.f);
        v.w = (e0 + 3 == e1) ? p1 : ((e0 + 3 == e2) ? p2 : 0.f);
        *(float4*)(out + (size_t)(m0 + t) * NE + e0) = v;
    }
}

extern "C" void kernel_launch(void* const* d_in, const int* in_sizes, int n_in,
                              void* d_out, int out_size, void* d_ws, size_t ws_size,
                              hipStream_t stream) {
    const float* A     = (const float*)d_in[0];
    const float* noise = (const float*)d_in[1];
    const float* Wr    = (const float*)d_in[2];
    const float* br    = (const float*)d_in[3];
    const float* Wn    = (const float*)d_in[4];
    const float* bn    = (const float*)d_in[5];
    float* out = (float*)d_out;

    short* Bh = (short*)d_ws;              // 131072 bf16 = 256 KB
    short* Bl = Bh + W_ELEMS;              // 256 KB more

    prepack_w<<<dim3(W_ELEMS / 8 / 256), dim3(256), 0, stream>>>(Wr, Wn, Bh, Bl);
    router_mfma<<<dim3(T_TOKENS / M_TILE), dim3(256), 0, stream>>>(A, noise, br, bn, Bh, Bl, out);
}